// Round 8
// baseline (396.177 us; speedup 1.0000x reference)
//
#include <hip/hip_runtime.h>
#include <hip/hip_bf16.h>
#include <math.h>

#define T_TOK 8192
#define D_MODEL 2048
#define N_EXP 16
#define CAP 512
#define NSEG (T_TOK / 64)           // 128
#define SMSTRIDE 130                // u64 stride per expert row (16B-aligned rows)
#define PSTRIDE 132                 // int stride per expert row (8B-aligned rows)

// ws layout (bytes):
// aff:      0       .. 524288    float[T_TOK][16]
// pref:     524288  .. +65536    u64[T_TOK]
// probs:    589824  .. +524288   float[T_TOK][16]
// segmask0: 1114112 .. +16384    u64[16][128]
// evt:      1130496 .. +128      int[32] (evp[16], evf[16])
// t2e:      1130624 .. +8192     u8[T_TOK]
// bcnt:     1138816 .. +2048     int[32][16]

__device__ __forceinline__ unsigned int f2ord(float f) {
    unsigned int b = __float_as_uint(f);
    return (b & 0x80000000u) ? ~b : (b | 0x80000000u);
}

// ---------------- Kernel 1: GEMM, W K-chunks double-buffered in LDS ----------------
// 1024 blocks x 256 thr (4 waves); wave owns 2 tokens; lane slices K (4 floats/chunk).
// 32 KB LDS, 4 blocks/CU -> 16 waves/CU.
__global__ __launch_bounds__(256, 4) void gemm_aff_kernel(
    const float* __restrict__ feat, const float* __restrict__ W,
    float* __restrict__ aff)
{
    __shared__ float w_lds[2][N_EXP][256];   // 2 x 16 KB

    const int tid  = threadIdx.x;
    const int wave = tid >> 6, lane = tid & 63;
    const int tbase = blockIdx.x * 8 + wave * 2;

    const int se  = tid >> 6;     // staging expert sub-row
    const int sc4 = tid & 63;     // staging col (float4)

    const float* fbase = feat + (size_t)tbase * D_MODEL + lane * 4;

    float acc[32];   // acc[r*16+e], r in 0..1
    #pragma unroll
    for (int i = 0; i < 32; ++i) acc[i] = 0.f;

    float4 wreg[4];
    #pragma unroll
    for (int q = 0; q < 4; ++q)
        wreg[q] = *(const float4*)(W + (size_t)(q * 4 + se) * D_MODEL + sc4 * 4);
    #pragma unroll
    for (int q = 0; q < 4; ++q)
        *(float4*)&w_lds[0][q * 4 + se][sc4 * 4] = wreg[q];
    #pragma unroll
    for (int q = 0; q < 4; ++q)
        wreg[q] = *(const float4*)(W + (size_t)(q * 4 + se) * D_MODEL + 256 + sc4 * 4);

    float4 cur[2], nxt[2];
    #pragma unroll
    for (int r = 0; r < 2; ++r)
        cur[r] = *(const float4*)(fbase + (size_t)r * D_MODEL);

    __syncthreads();

    #pragma unroll
    for (int j = 0; j < 8; ++j) {           // 8 K-chunks of 256 floats
        const int buf = j & 1;
        if (j < 7) {
            #pragma unroll
            for (int r = 0; r < 2; ++r)
                nxt[r] = *(const float4*)(fbase + (size_t)r * D_MODEL + (j + 1) * 256);
        }
        #pragma unroll
        for (int e = 0; e < N_EXP; ++e) {
            float4 wv = *(const float4*)&w_lds[buf][e][lane * 4];
            #pragma unroll
            for (int r = 0; r < 2; ++r) {
                acc[r * 16 + e] += cur[r].x * wv.x;
                acc[r * 16 + e] += cur[r].y * wv.y;
                acc[r * 16 + e] += cur[r].z * wv.z;
                acc[r * 16 + e] += cur[r].w * wv.w;
            }
        }
        if (j < 7) {
            #pragma unroll
            for (int q = 0; q < 4; ++q)
                *(float4*)&w_lds[buf ^ 1][q * 4 + se][sc4 * 4] = wreg[q];
            if (j < 6) {
                #pragma unroll
                for (int q = 0; q < 4; ++q)
                    wreg[q] = *(const float4*)(W + (size_t)(q * 4 + se) * D_MODEL + (j + 2) * 256 + sc4 * 4);
            }
        }
        __syncthreads();
        #pragma unroll
        for (int r = 0; r < 2; ++r) cur[r] = nxt[r];
    }

    // halving butterfly: 32 slots -> 1 slot over lane bits 0..4, then fold bit 5
    #pragma unroll
    for (int step = 0; step < 5; ++step) {
        const int m    = 1 << step;
        const int half = 32 >> (step + 1);
        const bool hi  = (lane & m) != 0;
        #pragma unroll
        for (int jj = 0; jj < half; ++jj) {
            float send = hi ? acc[jj] : acc[jj + half];
            float recv = __shfl_xor(send, m, 64);
            acc[jj] = (hi ? acc[jj + half] : acc[jj]) + recv;
        }
    }
    acc[0] += __shfl_xor(acc[0], 32, 64);   // fold K-halves (lane bit 5)
    const int slot = ((lane & 1) << 4) | (((lane >> 1) & 1) << 3) | (((lane >> 2) & 1) << 2)
                   | (((lane >> 3) & 1) << 1) | ((lane >> 4) & 1);
    if (lane < 32) {
        const int r = slot >> 4, e = slot & 15;
        aff[(size_t)(tbase + r) * N_EXP + e] = acc[0];
    }
}

// ---------------- Kernel 2: bias + softmax + pref lists + initial segment masks ----------------
__global__ __launch_bounds__(256) void finalize_kernel(
    const float* __restrict__ aff_in, const float* __restrict__ bias,
    unsigned long long* __restrict__ pref, float* __restrict__ probs,
    unsigned long long* __restrict__ segmask0)
{
    const int tid = threadIdx.x;
    const int t = blockIdx.x * 256 + tid;
    const int wave = tid >> 6, lane = tid & 63;

    float aff[N_EXP];
    const float4* p = (const float4*)(aff_in + (size_t)t * N_EXP);
    #pragma unroll
    for (int q = 0; q < 4; ++q) {
        float4 v = p[q];
        aff[q*4+0] = v.x; aff[q*4+1] = v.y; aff[q*4+2] = v.z; aff[q*4+3] = v.w;
    }
    #pragma unroll
    for (int e = 0; e < N_EXP; ++e) aff[e] += bias[e];

    float m = aff[0];
    #pragma unroll
    for (int e = 1; e < N_EXP; ++e) m = fmaxf(m, aff[e]);
    float s = 0.f;
    #pragma unroll
    for (int e = 0; e < N_EXP; ++e) s += __expf(aff[e] - m);

    float4* pr = (float4*)(probs + (size_t)t * N_EXP);
    #pragma unroll
    for (int q = 0; q < 4; ++q) {
        float4 v;
        v.x = __expf(aff[q*4+0] - m) / s;
        v.y = __expf(aff[q*4+1] - m) / s;
        v.z = __expf(aff[q*4+2] - m) / s;
        v.w = __expf(aff[q*4+3] - m) / s;
        pr[q] = v;
    }

    unsigned long long key[N_EXP];
    #pragma unroll
    for (int j = 0; j < N_EXP; ++j)
        key[j] = ((unsigned long long)f2ord(aff[j]) << 4) | (unsigned long long)(15 - j);
    unsigned long long pk = 0ull;
    unsigned int used = 0;
    for (int r = 0; r < N_EXP; ++r) {
        unsigned long long bk = 0ull; int be = 0;
        for (int j = 0; j < N_EXP; ++j)
            if (!((used >> j) & 1u) && key[j] > bk) { bk = key[j]; be = j; }
        used |= (1u << be);
        pk = (pk << 4) | (unsigned long long)be;
    }
    pref[t] = pk;

    // initial segment masks: wave w of block b covers segment b*4+w exactly
    const int c = (int)(pk >> 60);
    #pragma unroll
    for (int e = 0; e < N_EXP; ++e) {
        unsigned long long mm = __ballot(c == e);
        if (lane == e) segmask0[(size_t)e * NSEG + blockIdx.x * 4 + wave] = mm;
    }
}

// ---------------- Kernel 3: fill-event schedule (1 block, 512 thr) ----------------
__global__ __launch_bounds__(512) void events_kernel(
    const unsigned long long* __restrict__ pref,
    const unsigned long long* __restrict__ segmask0,
    int* __restrict__ evt)
{
    __shared__ unsigned long long segmask[N_EXP * SMSTRIDE];  // 16.6 KB
    __shared__ int pseg[N_EXP * PSTRIDE];                     // 8.4 KB
    __shared__ unsigned short queue[T_TOK];                   // 16 KB
    __shared__ int rem_cap[N_EXP], fparr[N_EXP];
    __shared__ int s_avail, s_pmin, s_fe, s_seglo, s_qn;
    __shared__ int evp[N_EXP], evf[N_EXP];

    const int tid  = threadIdx.x;
    const int wave = tid >> 6, lane = tid & 63;
    const unsigned long long lt_mask = (1ull << lane) - 1ull;

    for (int i = tid; i < N_EXP * NSEG; i += 512)
        segmask[(i >> 7) * SMSTRIDE + (i & 127)] = segmask0[i];
    if (tid < N_EXP) rem_cap[tid] = CAP;
    if (tid == 0) { s_avail = 0xFFFF; s_seglo = 0; }
    __syncthreads();

    for (int round = 0; round < N_EXP; ++round) {
        const unsigned int avail = (unsigned int)s_avail;
        const int seglo = s_seglo;

        // ---- A: packed pair-sum scan (experts wave, wave+8 in one u64) + locate
        const int e0 = wave, e1 = wave + 8;
        const int s0 = 2 * lane, s1 = s0 + 1;
        unsigned long long m00 = segmask[e0 * SMSTRIDE + s0];
        unsigned long long m01 = segmask[e0 * SMSTRIDE + s1];
        unsigned long long m10 = segmask[e1 * SMSTRIDE + s0];
        unsigned long long m11 = segmask[e1 * SMSTRIDE + s1];
        const int c00 = (s0 >= seglo) ? (int)__popcll(m00) : 0;
        const int c01 = (s1 >= seglo) ? (int)__popcll(m01) : 0;
        const int c10 = (s0 >= seglo) ? (int)__popcll(m10) : 0;
        const int c11 = (s1 >= seglo) ? (int)__popcll(m11) : 0;

        unsigned long long v = (unsigned long long)(unsigned)(c00 + c01)
                             | ((unsigned long long)(unsigned)(c10 + c11) << 32);
        unsigned long long inc = v;
        #pragma unroll
        for (int d = 1; d < 64; d <<= 1) {
            unsigned long long o = __shfl_up(inc, (unsigned)d, 64);
            if (lane >= d) inc += o;
        }
        const unsigned long long exc = inc - v;
        const int ex0 = (int)(exc & 0xffffffffull);
        const int ex1 = (int)(exc >> 32);

        *(unsigned long long*)&pseg[e0 * PSTRIDE + s0] =
            (unsigned long long)(unsigned)ex0 | ((unsigned long long)(unsigned)(ex0 + c00) << 32);
        *(unsigned long long*)&pseg[e1 * PSTRIDE + s0] =
            (unsigned long long)(unsigned)ex1 | ((unsigned long long)(unsigned)(ex1 + c10) << 32);

        #pragma unroll
        for (int ee = 0; ee < 2; ++ee) {
            const int e   = ee ? e1 : e0;
            const int exl = ee ? ex1 : ex0;
            const int ca  = ee ? c10 : c00;
            const int cb  = ee ? c11 : c01;
            int fp = 0x7FFFFFFF;
            if ((avail >> e) & 1u) {
                const int need = rem_cap[e];
                const bool cross = (exl < need) && (need <= exl + ca + cb);
                int sstar = 0, kk = 0;
                if (cross) {
                    if (need <= exl + ca) { sstar = s0; kk = need - exl; }
                    else                  { sstar = s1; kk = need - exl - ca; }
                }
                unsigned long long b = __ballot(cross);
                if (b) {
                    int l2 = __builtin_ctzll(b);
                    int ss = __shfl(sstar, l2, 64);
                    int k2 = __shfl(kk,    l2, 64);
                    unsigned long long mm = segmask[e * SMSTRIDE + ss];
                    int rr = (int)__popcll(mm & lt_mask);
                    bool hit = ((mm >> lane) & 1ull) && (rr == k2 - 1);
                    unsigned long long hb = __ballot(hit);
                    fp = ss * 64 + __builtin_ctzll(hb);
                }
            }
            if (lane == 0) fparr[e] = fp;
        }
        __syncthreads();

        // ---- B: earliest fill event
        if (tid == 0) {
            int pm = 0x7FFFFFFF, f = 0;
            #pragma unroll
            for (int e = 0; e < N_EXP; ++e)
                if (fparr[e] < pm) { pm = fparr[e]; f = e; }
            s_pmin = pm; s_fe = f;
        }
        __syncthreads();
        const int pmin = s_pmin, fe = s_fe;
        const int segF = pmin >> 6;

        // ---- C: capacity update + physical prune of boundary segment
        if (tid < N_EXP) {
            const int e = tid;
            unsigned long long mlep = ((pmin & 63) == 63) ? ~0ull
                                      : ((1ull << ((pmin & 63) + 1)) - 1ull);
            unsigned long long mm = segmask[e * SMSTRIDE + segF];
            rem_cap[e] -= pseg[e * PSTRIDE + segF] + (int)__popcll(mm & mlep);
            segmask[e * SMSTRIDE + segF] = mm & ~mlep;
        }
        if (tid == 0) {
            evp[round] = pmin; evf[round] = fe;
            s_avail = (int)(avail & ~(1u << fe));
            s_seglo = segF;
            s_qn = 0;
        }
        __syncthreads();

        // ---- D: queue-based rewalk of the filled expert's tail tokens
        if (round < N_EXP - 1) {
            if (tid >= segF && tid < NSEG) {
                unsigned long long mm = segmask[fe * SMSTRIDE + tid];
                if (mm) {
                    segmask[fe * SMSTRIDE + tid] = 0ull;
                    int n = (int)__popcll(mm);
                    int off = atomicAdd(&s_qn, n);
                    int base = tid << 6;
                    while (mm) {
                        int i = __builtin_ctzll(mm); mm &= mm - 1ull;
                        queue[off++] = (unsigned short)(base | i);
                    }
                }
            }
            __syncthreads();
            const unsigned int navail = avail & ~(1u << fe);
            const int qn = s_qn;
            for (int qi = tid; qi < qn; qi += 512) {
                int ent = queue[qi];
                int s = ent >> 6, i = ent & 63;
                unsigned long long pp = pref[s * 64 + i];
                int e2 = (int)(pp >> 60);
                while (!((navail >> e2) & 1u)) { pp <<= 4; e2 = (int)(pp >> 60); }
                atomicOr(&segmask[e2 * SMSTRIDE + s], 1ull << i);
            }
        }
        __syncthreads();
    }

    if (tid < N_EXP) { evt[tid] = evp[tid]; evt[N_EXP + tid] = evf[tid]; }
}

// ---------------- Kernel 4: final choice per token + per-block expert counts ----------------
__global__ __launch_bounds__(256) void choice_kernel(
    const unsigned long long* __restrict__ pref, const int* __restrict__ evt,
    unsigned char* __restrict__ t2e, int* __restrict__ bcnt)
{
    __shared__ int evp[N_EXP], evf[N_EXP];
    __shared__ int sc[4][N_EXP];
    const int tid = threadIdx.x, b = blockIdx.x;
    const int wave = tid >> 6, lane = tid & 63;
    if (tid < N_EXP) evp[tid] = evt[tid];
    else if (tid < 2 * N_EXP) evf[tid - N_EXP] = evt[tid];
    __syncthreads();

    const int t = b * 256 + tid;
    unsigned int mask = 0xFFFFu;
    #pragma unroll
    for (int j = 0; j < N_EXP; ++j)
        if (evp[j] < t) mask &= ~(1u << evf[j]);

    unsigned long long pp = pref[t];
    int e = (int)(pp >> 60);
    while (!((mask >> e) & 1u)) { pp <<= 4; e = (int)(pp >> 60); }
    t2e[t] = (unsigned char)e;

    #pragma unroll
    for (int e2 = 0; e2 < N_EXP; ++e2) {
        unsigned long long mm = __ballot(e == e2);
        if (lane == e2) sc[wave][e2] = (int)__popcll(mm);
    }
    __syncthreads();
    if (tid < N_EXP)
        bcnt[b * N_EXP + tid] = sc[0][tid] + sc[1][tid] + sc[2][tid] + sc[3][tid];
}

// ---------------- Kernel 5: ranks + write out0/out1 ----------------
__global__ __launch_bounds__(256) void writeout_kernel(
    const unsigned char* __restrict__ t2e, const int* __restrict__ bcnt,
    const float* __restrict__ probs,
    float* __restrict__ out0, float* __restrict__ out1)
{
    __shared__ int base[N_EXP];
    __shared__ int sc[4][N_EXP];
    const int tid = threadIdx.x, b = blockIdx.x;
    const int wave = tid >> 6, lane = tid & 63;
    const unsigned long long lt_mask = (1ull << lane) - 1ull;

    const int t = b * 256 + tid;
    const int c = (int)t2e[t];

    unsigned long long own = 0ull;
    #pragma unroll
    for (int e2 = 0; e2 < N_EXP; ++e2) {
        unsigned long long mm = __ballot(c == e2);
        if (c == e2) own = mm;
        if (lane == e2) sc[wave][e2] = (int)__popcll(mm);
    }
    if (tid < N_EXP) {
        int s = 0;
        for (int b2 = 0; b2 < b; ++b2) s += bcnt[b2 * N_EXP + tid];
        base[tid] = s;
    }
    __syncthreads();

    int rank = (int)__popcll(own & lt_mask);
    for (int w2 = 0; w2 < wave; ++w2) rank += sc[w2][c];
    const int pos = base[c] + rank;
    out0[c * CAP + pos] = (float)t;
    out1[t] = probs[(size_t)t * N_EXP + c];
}

extern "C" void kernel_launch(void* const* d_in, const int* in_sizes, int n_in,
                              void* d_out, int out_size, void* d_ws, size_t ws_size,
                              hipStream_t stream) {
    const float* feat = (const float*)d_in[0];
    const float* W    = (const float*)d_in[1];
    const float* bias = (const float*)d_in[2];

    float* out = (float*)d_out;
    char*  ws  = (char*)d_ws;

    float* aff                   = (float*)ws;
    unsigned long long* pref     = (unsigned long long*)(ws + 524288);
    float* probs                 = (float*)(ws + 589824);
    unsigned long long* segmask0 = (unsigned long long*)(ws + 1114112);
    int* evt                     = (int*)(ws + 1130496);
    unsigned char* t2e           = (unsigned char*)(ws + 1130624);
    int* bcnt                    = (int*)(ws + 1138816);

    hipLaunchKernelGGL(gemm_aff_kernel, dim3(1024), dim3(256), 0, stream,
                       feat, W, aff);
    hipLaunchKernelGGL(finalize_kernel, dim3(T_TOK / 256), dim3(256), 0, stream,
                       aff, bias, pref, probs, segmask0);
    hipLaunchKernelGGL(events_kernel, dim3(1), dim3(512), 0, stream,
                       pref, segmask0, evt);
    hipLaunchKernelGGL(choice_kernel, dim3(T_TOK / 256), dim3(256), 0, stream,
                       pref, evt, t2e, bcnt);
    hipLaunchKernelGGL(writeout_kernel, dim3(T_TOK / 256), dim3(256), 0, stream,
                       t2e, bcnt, probs, out, out + T_TOK);
}

// Round 9
// 202.358 us; speedup vs baseline: 1.9578x; 1.9578x over previous
//
#include <hip/hip_runtime.h>
#include <hip/hip_bf16.h>
#include <math.h>

#define T_TOK 8192
#define D_MODEL 2048
#define N_EXP 16
#define CAP 512
#define NSEG (T_TOK / 64)           // 128
#define SMSTRIDE 130                // u64 stride per expert row
#define PSTRIDE 132                 // int stride per expert row

// ws layout (bytes):
// aff:      0       .. 524288    float[T_TOK][16]
// pref:     524288  .. +65536    u64[T_TOK]
// probs:    589824  .. +524288   float[T_TOK][16]
// segmask0: 1114112 .. +16384    u64[16][128]
// evt:      1130496 .. +128      int[32] (evp[16], evf[16])
// t2e:      1130624 .. +8192     u8[T_TOK]
// bcnt:     1138816 .. +2048     int[32][16]

__device__ __forceinline__ unsigned int f2ord(float f) {
    unsigned int b = __float_as_uint(f);
    return (b & 0x80000000u) ? ~b : (b | 0x80000000u);
}

// ---------------- Kernel 1: GEMM, W K-chunks double-buffered in LDS ----------------
// 1024 blocks x 256 thr (4 waves); wave owns 2 tokens; lane slices K (4 floats/chunk).
// launch_bounds(256,2): VGPR cap 256 (actual ~100, no spill); LDS 32 KB -> ~5 blocks/CU runtime.
__global__ __launch_bounds__(256, 2) void gemm_aff_kernel(
    const float* __restrict__ feat, const float* __restrict__ W,
    float* __restrict__ aff)
{
    __shared__ float w_lds[2][N_EXP][256];   // 2 x 16 KB

    const int tid  = threadIdx.x;
    const int wave = tid >> 6, lane = tid & 63;
    const int tbase = blockIdx.x * 8 + wave * 2;

    const int se  = tid >> 6;     // staging expert sub-row
    const int sc4 = tid & 63;     // staging col (float4)

    const float* fbase = feat + (size_t)tbase * D_MODEL + lane * 4;

    float acc[32];   // acc[r*16+e], r in 0..1
    #pragma unroll
    for (int i = 0; i < 32; ++i) acc[i] = 0.f;

    float4 wreg[4];
    #pragma unroll
    for (int q = 0; q < 4; ++q)
        wreg[q] = *(const float4*)(W + (size_t)(q * 4 + se) * D_MODEL + sc4 * 4);
    #pragma unroll
    for (int q = 0; q < 4; ++q)
        *(float4*)&w_lds[0][q * 4 + se][sc4 * 4] = wreg[q];
    #pragma unroll
    for (int q = 0; q < 4; ++q)
        wreg[q] = *(const float4*)(W + (size_t)(q * 4 + se) * D_MODEL + 256 + sc4 * 4);

    float4 cur[2], nxt[2];
    #pragma unroll
    for (int r = 0; r < 2; ++r)
        cur[r] = *(const float4*)(fbase + (size_t)r * D_MODEL);

    __syncthreads();

    #pragma unroll
    for (int j = 0; j < 8; ++j) {           // 8 K-chunks of 256 floats
        const int buf = j & 1;
        if (j < 7) {
            #pragma unroll
            for (int r = 0; r < 2; ++r)
                nxt[r] = *(const float4*)(fbase + (size_t)r * D_MODEL + (j + 1) * 256);
        }
        #pragma unroll
        for (int e = 0; e < N_EXP; ++e) {
            float4 wv = *(const float4*)&w_lds[buf][e][lane * 4];
            #pragma unroll
            for (int r = 0; r < 2; ++r) {
                acc[r * 16 + e] += cur[r].x * wv.x;
                acc[r * 16 + e] += cur[r].y * wv.y;
                acc[r * 16 + e] += cur[r].z * wv.z;
                acc[r * 16 + e] += cur[r].w * wv.w;
            }
        }
        if (j < 7) {
            #pragma unroll
            for (int q = 0; q < 4; ++q)
                *(float4*)&w_lds[buf ^ 1][q * 4 + se][sc4 * 4] = wreg[q];
            if (j < 6) {
                #pragma unroll
                for (int q = 0; q < 4; ++q)
                    wreg[q] = *(const float4*)(W + (size_t)(q * 4 + se) * D_MODEL + (j + 2) * 256 + sc4 * 4);
            }
        }
        __syncthreads();
        #pragma unroll
        for (int r = 0; r < 2; ++r) cur[r] = nxt[r];
    }

    // halving butterfly: 32 slots -> 1 slot over lane bits 0..4, then fold bit 5 (verified r8)
    #pragma unroll
    for (int step = 0; step < 5; ++step) {
        const int m    = 1 << step;
        const int half = 32 >> (step + 1);
        const bool hi  = (lane & m) != 0;
        #pragma unroll
        for (int jj = 0; jj < half; ++jj) {
            float send = hi ? acc[jj] : acc[jj + half];
            float recv = __shfl_xor(send, m, 64);
            acc[jj] = (hi ? acc[jj + half] : acc[jj]) + recv;
        }
    }
    acc[0] += __shfl_xor(acc[0], 32, 64);   // fold K-halves (lane bit 5)
    const int slot = ((lane & 1) << 4) | (((lane >> 1) & 1) << 3) | (((lane >> 2) & 1) << 2)
                   | (((lane >> 3) & 1) << 1) | ((lane >> 4) & 1);
    if (lane < 32) {
        const int r = slot >> 4, e = slot & 15;
        aff[(size_t)(tbase + r) * N_EXP + e] = acc[0];
    }
}

// ---------------- Kernel 2: bias + softmax + pref lists + initial segment masks ----------------
// 128 blocks x 64 thr: block b == segment b (one wave), spreads the selection sort over CUs.
__global__ __launch_bounds__(64) void finalize_kernel(
    const float* __restrict__ aff_in, const float* __restrict__ bias,
    unsigned long long* __restrict__ pref, float* __restrict__ probs,
    unsigned long long* __restrict__ segmask0)
{
    const int lane = threadIdx.x;
    const int t = blockIdx.x * 64 + lane;

    float aff[N_EXP];
    const float4* p = (const float4*)(aff_in + (size_t)t * N_EXP);
    #pragma unroll
    for (int q = 0; q < 4; ++q) {
        float4 v = p[q];
        aff[q*4+0] = v.x; aff[q*4+1] = v.y; aff[q*4+2] = v.z; aff[q*4+3] = v.w;
    }
    #pragma unroll
    for (int e = 0; e < N_EXP; ++e) aff[e] += bias[e];

    float m = aff[0];
    #pragma unroll
    for (int e = 1; e < N_EXP; ++e) m = fmaxf(m, aff[e]);
    float s = 0.f;
    #pragma unroll
    for (int e = 0; e < N_EXP; ++e) s += __expf(aff[e] - m);

    float4* pr = (float4*)(probs + (size_t)t * N_EXP);
    #pragma unroll
    for (int q = 0; q < 4; ++q) {
        float4 v;
        v.x = __expf(aff[q*4+0] - m) / s;
        v.y = __expf(aff[q*4+1] - m) / s;
        v.z = __expf(aff[q*4+2] - m) / s;
        v.w = __expf(aff[q*4+3] - m) / s;
        pr[q] = v;
    }

    unsigned long long key[N_EXP];
    #pragma unroll
    for (int j = 0; j < N_EXP; ++j)
        key[j] = ((unsigned long long)f2ord(aff[j]) << 4) | (unsigned long long)(15 - j);
    unsigned long long pk = 0ull;
    unsigned int used = 0;
    for (int r = 0; r < N_EXP; ++r) {
        unsigned long long bk = 0ull; int be = 0;
        for (int j = 0; j < N_EXP; ++j)
            if (!((used >> j) & 1u) && key[j] > bk) { bk = key[j]; be = j; }
        used |= (1u << be);
        pk = (pk << 4) | (unsigned long long)be;
    }
    pref[t] = pk;

    // initial segment masks: this block IS segment blockIdx.x
    const int c = (int)(pk >> 60);
    #pragma unroll
    for (int e = 0; e < N_EXP; ++e) {
        unsigned long long mm = __ballot(c == e);
        if (lane == e) segmask0[(size_t)e * NSEG + blockIdx.x] = mm;
    }
}

// ---------------- Kernel 3: fill-event schedule (1 block, 512 thr) ----------------
__global__ __launch_bounds__(512) void events_kernel(
    const unsigned long long* __restrict__ pref,
    const unsigned long long* __restrict__ segmask0,
    int* __restrict__ evt)
{
    __shared__ unsigned long long segmask[N_EXP * SMSTRIDE];
    __shared__ int pseg[N_EXP * PSTRIDE];
    __shared__ unsigned short queue[T_TOK];
    __shared__ int rem_cap[N_EXP], fparr[N_EXP];
    __shared__ int s_avail, s_pmin, s_fe, s_seglo, s_qn;
    __shared__ int evp[N_EXP], evf[N_EXP];

    const int tid  = threadIdx.x;
    const int wave = tid >> 6, lane = tid & 63;
    const unsigned long long lt_mask = (1ull << lane) - 1ull;

    for (int i = tid; i < N_EXP * NSEG; i += 512)
        segmask[(i >> 7) * SMSTRIDE + (i & 127)] = segmask0[i];
    if (tid < N_EXP) rem_cap[tid] = CAP;
    if (tid == 0) { s_avail = 0xFFFF; s_seglo = 0; }
    __syncthreads();

    for (int round = 0; round < N_EXP; ++round) {
        const unsigned int avail = (unsigned int)s_avail;
        const int seglo = s_seglo;

        // ---- A: packed pair-sum scan (experts wave, wave+8 in one u64) + locate
        const int e0 = wave, e1 = wave + 8;
        const int s0 = 2 * lane, s1 = s0 + 1;
        unsigned long long m00 = segmask[e0 * SMSTRIDE + s0];
        unsigned long long m01 = segmask[e0 * SMSTRIDE + s1];
        unsigned long long m10 = segmask[e1 * SMSTRIDE + s0];
        unsigned long long m11 = segmask[e1 * SMSTRIDE + s1];
        const int c00 = (s0 >= seglo) ? (int)__popcll(m00) : 0;
        const int c01 = (s1 >= seglo) ? (int)__popcll(m01) : 0;
        const int c10 = (s0 >= seglo) ? (int)__popcll(m10) : 0;
        const int c11 = (s1 >= seglo) ? (int)__popcll(m11) : 0;

        unsigned long long v = (unsigned long long)(unsigned)(c00 + c01)
                             | ((unsigned long long)(unsigned)(c10 + c11) << 32);
        unsigned long long inc = v;
        #pragma unroll
        for (int d = 1; d < 64; d <<= 1) {
            unsigned long long o = __shfl_up(inc, (unsigned)d, 64);
            if (lane >= d) inc += o;
        }
        const unsigned long long exc = inc - v;
        const int ex0 = (int)(exc & 0xffffffffull);
        const int ex1 = (int)(exc >> 32);

        *(unsigned long long*)&pseg[e0 * PSTRIDE + s0] =
            (unsigned long long)(unsigned)ex0 | ((unsigned long long)(unsigned)(ex0 + c00) << 32);
        *(unsigned long long*)&pseg[e1 * PSTRIDE + s0] =
            (unsigned long long)(unsigned)ex1 | ((unsigned long long)(unsigned)(ex1 + c10) << 32);

        #pragma unroll
        for (int ee = 0; ee < 2; ++ee) {
            const int e   = ee ? e1 : e0;
            const int exl = ee ? ex1 : ex0;
            const int ca  = ee ? c10 : c00;
            const int cb  = ee ? c11 : c01;
            int fp = 0x7FFFFFFF;
            if ((avail >> e) & 1u) {
                const int need = rem_cap[e];
                const bool cross = (exl < need) && (need <= exl + ca + cb);
                int sstar = 0, kk = 0;
                if (cross) {
                    if (need <= exl + ca) { sstar = s0; kk = need - exl; }
                    else                  { sstar = s1; kk = need - exl - ca; }
                }
                unsigned long long b = __ballot(cross);
                if (b) {
                    int l2 = __builtin_ctzll(b);
                    int ss = __shfl(sstar, l2, 64);
                    int k2 = __shfl(kk,    l2, 64);
                    unsigned long long mm = segmask[e * SMSTRIDE + ss];
                    int rr = (int)__popcll(mm & lt_mask);
                    bool hit = ((mm >> lane) & 1ull) && (rr == k2 - 1);
                    unsigned long long hb = __ballot(hit);
                    fp = ss * 64 + __builtin_ctzll(hb);
                }
            }
            if (lane == 0) fparr[e] = fp;
        }
        __syncthreads();

        // ---- B: earliest fill event
        if (tid == 0) {
            int pm = 0x7FFFFFFF, f = 0;
            #pragma unroll
            for (int e = 0; e < N_EXP; ++e)
                if (fparr[e] < pm) { pm = fparr[e]; f = e; }
            s_pmin = pm; s_fe = f;
        }
        __syncthreads();
        const int pmin = s_pmin, fe = s_fe;
        const int segF = pmin >> 6;

        // ---- C: capacity update + physical prune of boundary segment
        if (tid < N_EXP) {
            const int e = tid;
            unsigned long long mlep = ((pmin & 63) == 63) ? ~0ull
                                      : ((1ull << ((pmin & 63) + 1)) - 1ull);
            unsigned long long mm = segmask[e * SMSTRIDE + segF];
            rem_cap[e] -= pseg[e * PSTRIDE + segF] + (int)__popcll(mm & mlep);
            segmask[e * SMSTRIDE + segF] = mm & ~mlep;
        }
        if (tid == 0) {
            evp[round] = pmin; evf[round] = fe;
            s_avail = (int)(avail & ~(1u << fe));
            s_seglo = segF;
            s_qn = 0;
        }
        __syncthreads();

        // ---- D: queue-based rewalk of the filled expert's tail tokens
        if (round < N_EXP - 1) {
            if (tid >= segF && tid < NSEG) {
                unsigned long long mm = segmask[fe * SMSTRIDE + tid];
                if (mm) {
                    segmask[fe * SMSTRIDE + tid] = 0ull;
                    int n = (int)__popcll(mm);
                    int off = atomicAdd(&s_qn, n);
                    int base = tid << 6;
                    while (mm) {
                        int i = __builtin_ctzll(mm); mm &= mm - 1ull;
                        queue[off++] = (unsigned short)(base | i);
                    }
                }
            }
            __syncthreads();
            const unsigned int navail = avail & ~(1u << fe);
            const int qn = s_qn;
            for (int qi = tid; qi < qn; qi += 512) {
                int ent = queue[qi];
                int s = ent >> 6, i = ent & 63;
                unsigned long long pp = pref[s * 64 + i];
                int e2 = (int)(pp >> 60);
                while (!((navail >> e2) & 1u)) { pp <<= 4; e2 = (int)(pp >> 60); }
                atomicOr(&segmask[e2 * SMSTRIDE + s], 1ull << i);
            }
        }
        __syncthreads();
    }

    if (tid < N_EXP) { evt[tid] = evp[tid]; evt[N_EXP + tid] = evf[tid]; }
}

// ---------------- Kernel 4: final choice per token + per-block expert counts ----------------
__global__ __launch_bounds__(256) void choice_kernel(
    const unsigned long long* __restrict__ pref, const int* __restrict__ evt,
    unsigned char* __restrict__ t2e, int* __restrict__ bcnt)
{
    __shared__ int evp[N_EXP], evf[N_EXP];
    __shared__ int sc[4][N_EXP];
    const int tid = threadIdx.x, b = blockIdx.x;
    const int wave = tid >> 6, lane = tid & 63;
    if (tid < N_EXP) evp[tid] = evt[tid];
    else if (tid < 2 * N_EXP) evf[tid - N_EXP] = evt[tid];
    __syncthreads();

    const int t = b * 256 + tid;
    unsigned int mask = 0xFFFFu;
    #pragma unroll
    for (int j = 0; j < N_EXP; ++j)
        if (evp[j] < t) mask &= ~(1u << evf[j]);

    unsigned long long pp = pref[t];
    int e = (int)(pp >> 60);
    while (!((mask >> e) & 1u)) { pp <<= 4; e = (int)(pp >> 60); }
    t2e[t] = (unsigned char)e;

    #pragma unroll
    for (int e2 = 0; e2 < N_EXP; ++e2) {
        unsigned long long mm = __ballot(e == e2);
        if (lane == e2) sc[wave][e2] = (int)__popcll(mm);
    }
    __syncthreads();
    if (tid < N_EXP)
        bcnt[b * N_EXP + tid] = sc[0][tid] + sc[1][tid] + sc[2][tid] + sc[3][tid];
}

// ---------------- Kernel 5: ranks + write out0/out1 ----------------
__global__ __launch_bounds__(256) void writeout_kernel(
    const unsigned char* __restrict__ t2e, const int* __restrict__ bcnt,
    const float* __restrict__ probs,
    float* __restrict__ out0, float* __restrict__ out1)
{
    __shared__ int base[N_EXP];
    __shared__ int sc[4][N_EXP];
    const int tid = threadIdx.x, b = blockIdx.x;
    const int wave = tid >> 6, lane = tid & 63;
    const unsigned long long lt_mask = (1ull << lane) - 1ull;

    const int t = b * 256 + tid;
    const int c = (int)t2e[t];

    unsigned long long own = 0ull;
    #pragma unroll
    for (int e2 = 0; e2 < N_EXP; ++e2) {
        unsigned long long mm = __ballot(c == e2);
        if (c == e2) own = mm;
        if (lane == e2) sc[wave][e2] = (int)__popcll(mm);
    }
    if (tid < N_EXP) {
        int s = 0;
        for (int b2 = 0; b2 < b; ++b2) s += bcnt[b2 * N_EXP + tid];
        base[tid] = s;
    }
    __syncthreads();

    int rank = (int)__popcll(own & lt_mask);
    for (int w2 = 0; w2 < wave; ++w2) rank += sc[w2][c];
    const int pos = base[c] + rank;
    out0[c * CAP + pos] = (float)t;
    out1[t] = probs[(size_t)t * N_EXP + c];
}

extern "C" void kernel_launch(void* const* d_in, const int* in_sizes, int n_in,
                              void* d_out, int out_size, void* d_ws, size_t ws_size,
                              hipStream_t stream) {
    const float* feat = (const float*)d_in[0];
    const float* W    = (const float*)d_in[1];
    const float* bias = (const float*)d_in[2];

    float* out = (float*)d_out;
    char*  ws  = (char*)d_ws;

    float* aff                   = (float*)ws;
    unsigned long long* pref     = (unsigned long long*)(ws + 524288);
    float* probs                 = (float*)(ws + 589824);
    unsigned long long* segmask0 = (unsigned long long*)(ws + 1114112);
    int* evt                     = (int*)(ws + 1130496);
    unsigned char* t2e           = (unsigned char*)(ws + 1130624);
    int* bcnt                    = (int*)(ws + 1138816);

    hipLaunchKernelGGL(gemm_aff_kernel, dim3(1024), dim3(256), 0, stream,
                       feat, W, aff);
    hipLaunchKernelGGL(finalize_kernel, dim3(NSEG), dim3(64), 0, stream,
                       aff, bias, pref, probs, segmask0);
    hipLaunchKernelGGL(events_kernel, dim3(1), dim3(512), 0, stream,
                       pref, segmask0, evt);
    hipLaunchKernelGGL(choice_kernel, dim3(T_TOK / 256), dim3(256), 0, stream,
                       pref, evt, t2e, bcnt);
    hipLaunchKernelGGL(writeout_kernel, dim3(T_TOK / 256), dim3(256), 0, stream,
                       t2e, bcnt, probs, out, out + T_TOK);
}